// Round 4
// baseline (106.467 us; speedup 1.0000x reference)
//
#include <hip/hip_runtime.h>
#include <math.h>

#define NB 512
#define NS 64
#define ND 2048
#define NP 1024   // ND/2

// ws layout (float offsets)
#define OFF_M0 0        // 131072 floats
#define OFF_M1 131072   // 131072 floats
#define OFF_QT 262144   // float4[1024][64] = 262144 floats (1 MB)

// ---------------- threefry2x32 (exact jax semantics, key=(0,42)) -------------
__device__ __forceinline__ unsigned rotl32(unsigned x, int d) {
    return (x << d) | (x >> (32 - d));
}

__device__ __forceinline__ void threefry2x32(unsigned k0, unsigned k1,
                                             unsigned& x0, unsigned& x1) {
    const unsigned ks0 = k0, ks1 = k1, ks2 = k0 ^ k1 ^ 0x1BD11BDAu;
    const int r0[4] = {13, 15, 26, 6};
    const int r1[4] = {17, 29, 16, 24};
    x0 += ks0; x1 += ks1;
#pragma unroll
    for (int i = 0; i < 4; ++i) { x0 += x1; x1 = rotl32(x1, r0[i]); x1 ^= x0; }
    x0 += ks1; x1 += ks2 + 1u;
#pragma unroll
    for (int i = 0; i < 4; ++i) { x0 += x1; x1 = rotl32(x1, r1[i]); x1 ^= x0; }
    x0 += ks2; x1 += ks0 + 2u;
#pragma unroll
    for (int i = 0; i < 4; ++i) { x0 += x1; x1 = rotl32(x1, r0[i]); x1 ^= x0; }
    x0 += ks0; x1 += ks1 + 3u;
#pragma unroll
    for (int i = 0; i < 4; ++i) { x0 += x1; x1 = rotl32(x1, r1[i]); x1 ^= x0; }
    x0 += ks1; x1 += ks2 + 4u;
#pragma unroll
    for (int i = 0; i < 4; ++i) { x0 += x1; x1 = rotl32(x1, r0[i]); x1 ^= x0; }
    x0 += ks2; x1 += ks0 + 5u;
}

// ---------------- K1: fused norms + softmax + M0/M1/Qt -----------------------
// 64 blocks x 1024 threads; block = srow. Each block redundantly computes all
// 64 inv-norms (exact original 16-thread pattern; amp is L2-shared per XCD)
// and its own E-row softmax (exact original wave pattern). Then thread = pair,
// serial t-sum with the exact round-0 inner expression. No R intermediate.
__global__ void __launch_bounds__(1024)
k_MQ(const float* __restrict__ amp, const float* __restrict__ ph,
     const float* __restrict__ G, const float* __restrict__ E,
     float* __restrict__ M0, float* __restrict__ M1, float* __restrict__ Qt) {
    __shared__ float norm2[NS];
    __shared__ float in_l[NS], W_l[NS];
    __shared__ float Gl[NS * 4];
    const int srow = blockIdx.x;
    const int tid = threadIdx.x;

    {   // norms: 64 rows x 16 threads, exact original summation order
        const int r = tid >> 4, sub = tid & 15;
        const float4* a4 = (const float4*)(amp + r * ND);
        float acc = 0.f;
#pragma unroll 8
        for (int i = 0; i < 32; ++i) {
            float4 v = a4[sub + 16 * i];
            acc += v.x * v.x + v.y * v.y + v.z * v.z + v.w * v.w;
        }
        acc += __shfl_down(acc, 8, 16);
        acc += __shfl_down(acc, 4, 16);
        acc += __shfl_down(acc, 2, 16);
        acc += __shfl_down(acc, 1, 16);
        if (sub == 0) norm2[r] = acc;
    }
    if (tid < NS * 4) Gl[tid] = G[tid];
    __syncthreads();
    if (tid < NS) {  // wave 0: inv-norm + softmax of this block's E row (exact)
        in_l[tid] = 1.0f / sqrtf(norm2[tid]);
        float e = E[srow * NS + tid];
        float m = e;
        for (int off = 32; off; off >>= 1) m = fmaxf(m, __shfl_down(m, off));
        m = __shfl(m, 0);
        float ex = expf(e - m);
        float sum = ex;
        for (int off = 32; off; off >>= 1) sum += __shfl_down(sum, off);
        sum = __shfl(sum, 0);
        W_l[tid] = ex / sum;
    }
    __syncthreads();

    // thread = pair p; serial t-sum (coalesced 512-B wave reads per t)
    const int p = tid;
    const float2* a2 = (const float2*)amp;
    const float2* p2 = (const float2*)ph;
    float a0 = 0.f, a1 = 0.f, b0 = 0.f, b1 = 0.f;
#pragma unroll 4
    for (int t = 0; t < NS; ++t) {
        float2 av = a2[t * NP + p];
        float2 pv = p2[t * NP + p];
        float in = in_l[t], w = W_l[t];
        float ra0 = av.x * in * (__cosf(pv.x) + __sinf(pv.x));
        float ra1 = av.y * in * (__cosf(pv.y) + __sinf(pv.y));
        float wr0 = w * ra0, wr1 = w * ra1;
        a0 += wr0 * Gl[4 * t + 0];
        b0 += wr0 * Gl[4 * t + 2];
        a1 += wr1 * Gl[4 * t + 1];
        b1 += wr1 * Gl[4 * t + 3];
    }
    ((float2*)(M0 + srow * ND))[p] = make_float2(a0, a1);
    ((float2*)(M1 + srow * ND))[p] = make_float2(b0, b1);
    ((float4*)Qt)[p * 64 + srow] =
        make_float4(a0 * a0 + a1 * a1, a0 * b0 + a1 * b1, b0 * b0 + b1 * b1, 0.f);
}

// ---------------- K2: logits + collapse + output, fully in-block -------------
// 128 blocks x 1024 threads; block = 4 B-rows. Wave w owns p in [64w, 64w+64):
// Qt read = coalesced 1 KB float4 line per (w,p); x rows staged in LDS.
// No pc-split -> no pglob -> no cross-block reduction -> single kernel.
__global__ void __launch_bounds__(1024)
k_out(const float* __restrict__ x, const float* __restrict__ Qt,
      const float* __restrict__ M0, const float* __restrict__ M1,
      float* __restrict__ out) {
    __shared__ float2 xs[4][NP];        // 32 KB
    __shared__ float part[16][4][64];   // 16 KB
    __shared__ int o_sh[4];
    const int rg = blockIdx.x;
    const int tid = threadIdx.x;
    const int r0 = rg * 4;

    // stage 4 x rows (coalesced float4: 2048 of them, 2 iters)
#pragma unroll
    for (int k = 0; k < 2; ++k) {
        const int idx = tid + 1024 * k;
        const int r = idx >> 9, i = idx & 511;
        float4 v = ((const float4*)(x + (r0 + r) * ND))[i];
        xs[r][2 * i]     = make_float2(v.x, v.y);
        xs[r][2 * i + 1] = make_float2(v.z, v.w);
    }
    __syncthreads();

    const int w = tid >> 6, s = tid & 63;
    {
        float acc[4] = {0.f, 0.f, 0.f, 0.f};
        const float4* qt4 = (const float4*)Qt + (w << 6) * 64 + s;
#pragma unroll 8
        for (int j = 0; j < 64; ++j) {
            float4 q = qt4[j * 64];          // coalesced 1 KB per wave
            const int pl = (w << 6) + j;
#pragma unroll
            for (int r = 0; r < 4; ++r) {
                float2 xv = xs[r][pl];       // LDS broadcast (wave-uniform addr)
                float qx = xv.x * xv.x, qy = 2.f * xv.x * xv.y, qz = xv.y * xv.y;
                acc[r] += qx * q.x + qy * q.y + qz * q.z;
            }
        }
#pragma unroll
        for (int r = 0; r < 4; ++r) part[w][r][s] = acc[r];
    }
    __syncthreads();

    if (tid < 256) {  // waves 0-3: row r0+rr; fixed-order reduce + gumbel-max
        const int rr = tid >> 6;
        const int row = r0 + rr;
        float l = 0.f;
#pragma unroll
        for (int k = 0; k < 16; ++k) l += part[k][rr][s];
        unsigned n = (unsigned)(row * NS + s);
        unsigned t0u = 0u, t1u = n;
        threefry2x32(0u, 42u, t0u, t1u);
        unsigned bits = t0u ^ t1u;
        float u = (float)(bits >> 9) * (1.0f / 8388608.0f);
        u = fmaxf(u, 1.17549435e-38f);
        float g = -logf(-logf(u));
        float best = l + g;
        int bi = s;
        for (int off = 32; off; off >>= 1) {
            float ov = __shfl_down(best, off);
            int oi = __shfl_down(bi, off);
            if (ov > best || (ov == best && oi < bi)) { best = ov; bi = oi; }
        }
        if (s == 0) o_sh[rr] = bi;
    }
    __syncthreads();

    // output: 4 rows x 512 float4, x from LDS, M0/M1 coalesced gather
#pragma unroll
    for (int k = 0; k < 2; ++k) {
        const int idx = tid + 1024 * k;
        const int r = idx >> 9, i = idx & 511;
        const int o = o_sh[r];
        float2 xa = xs[r][2 * i], xb = xs[r][2 * i + 1];
        float4 m0 = ((const float4*)(M0 + o * ND))[i];
        float4 m1 = ((const float4*)(M1 + o * ND))[i];
        float4 rr4;
        rr4.x = xa.x * m0.x + xa.y * m1.x;
        rr4.y = xa.x * m0.y + xa.y * m1.y;
        rr4.z = xb.x * m0.z + xb.y * m1.z;
        rr4.w = xb.x * m0.w + xb.y * m1.w;
        ((float4*)(out + (r0 + r) * ND))[i] = rr4;
    }
}

extern "C" void kernel_launch(void* const* d_in, const int* in_sizes, int n_in,
                              void* d_out, int out_size, void* d_ws, size_t ws_size,
                              hipStream_t stream) {
    const float* x   = (const float*)d_in[0];  // [512,2048]
    const float* amp = (const float*)d_in[1];  // [64,2048]
    const float* ph  = (const float*)d_in[2];  // [64,2048]
    const float* G   = (const float*)d_in[3];  // [64,2,2]
    const float* E   = (const float*)d_in[4];  // [64,64]
    float* out = (float*)d_out;
    float* ws = (float*)d_ws;

    float* M0 = ws + OFF_M0;
    float* M1 = ws + OFF_M1;
    float* Qt = ws + OFF_QT;

    k_MQ <<<64, 1024, 0, stream>>>(amp, ph, G, E, M0, M1, Qt);
    k_out<<<128, 1024, 0, stream>>>(x, Qt, M0, M1, out);
}

// Round 5
// 91.879 us; speedup vs baseline: 1.1588x; 1.1588x over previous
//
#include <hip/hip_runtime.h>
#include <math.h>

#define NB 512
#define NS 64
#define ND 2048
#define NP 1024   // ND/2

// ws layout (float offsets)
#define OFF_M0   0        // 131072 floats
#define OFF_M1   131072   // 131072 floats
#define OFF_QT   262144   // float4[1024][64] = 262144 floats (1 MB padded)
#define OFF_PART 524288   // [4][512][64] = 131072 floats

// ---------------- threefry2x32 (exact jax semantics, key=(0,42)) -------------
__device__ __forceinline__ unsigned rotl32(unsigned x, int d) {
    return (x << d) | (x >> (32 - d));
}

__device__ __forceinline__ void threefry2x32(unsigned k0, unsigned k1,
                                             unsigned& x0, unsigned& x1) {
    const unsigned ks0 = k0, ks1 = k1, ks2 = k0 ^ k1 ^ 0x1BD11BDAu;
    const int r0[4] = {13, 15, 26, 6};
    const int r1[4] = {17, 29, 16, 24};
    x0 += ks0; x1 += ks1;
#pragma unroll
    for (int i = 0; i < 4; ++i) { x0 += x1; x1 = rotl32(x1, r0[i]); x1 ^= x0; }
    x0 += ks1; x1 += ks2 + 1u;
#pragma unroll
    for (int i = 0; i < 4; ++i) { x0 += x1; x1 = rotl32(x1, r1[i]); x1 ^= x0; }
    x0 += ks2; x1 += ks0 + 2u;
#pragma unroll
    for (int i = 0; i < 4; ++i) { x0 += x1; x1 = rotl32(x1, r0[i]); x1 ^= x0; }
    x0 += ks0; x1 += ks1 + 3u;
#pragma unroll
    for (int i = 0; i < 4; ++i) { x0 += x1; x1 = rotl32(x1, r1[i]); x1 ^= x0; }
    x0 += ks1; x1 += ks2 + 4u;
#pragma unroll
    for (int i = 0; i < 4; ++i) { x0 += x1; x1 = rotl32(x1, r0[i]); x1 ^= x0; }
    x0 += ks2; x1 += ks0 + 5u;
}

// ---------------- K1: fused norms + softmax + M0/M1/Qt (R0 structure) --------
// 256 blocks x 1024 threads: srow = blk>>2, pair chunk = (blk&3)*256.
// Redundant norms per block (L2-shared amp), per-srow softmax, 4x t-split
// partials in LDS, ordered combine. Only change vs R0: Qt write is float4.
__global__ void __launch_bounds__(1024)
k_MQ(const float* __restrict__ amp, const float* __restrict__ ph,
     const float* __restrict__ G, const float* __restrict__ E,
     float* __restrict__ M0, float* __restrict__ M1, float* __restrict__ Qt) {
    __shared__ float norm2[NS];
    __shared__ float W_l[NS], in_l[NS];
    __shared__ float Gl[NS * 4];
    __shared__ float4 part4[4][256];   // 16 KB
    const int blk = blockIdx.x;
    const int tid = threadIdx.x;
    const int srow = blk >> 2;

    {   // redundant norms: 16 threads per amp row, exact original pattern
        const int r = tid >> 4, sub = tid & 15;
        const float4* a4 = (const float4*)(amp + r * ND);
        float acc = 0.f;
#pragma unroll 8
        for (int i = 0; i < 32; ++i) {
            float4 v = a4[sub + 16 * i];
            acc += v.x * v.x + v.y * v.y + v.z * v.z + v.w * v.w;
        }
        acc += __shfl_down(acc, 8, 16);
        acc += __shfl_down(acc, 4, 16);
        acc += __shfl_down(acc, 2, 16);
        acc += __shfl_down(acc, 1, 16);
        if (sub == 0) norm2[r] = acc;
    }
    if (tid < NS * 4) Gl[tid] = G[tid];
    __syncthreads();
    if (tid < NS) {  // wave 0: inv-norm + softmax of this block's E row
        in_l[tid] = 1.0f / sqrtf(norm2[tid]);
        float e = E[srow * NS + tid];
        float m = e;
        for (int off = 32; off; off >>= 1) m = fmaxf(m, __shfl_down(m, off));
        m = __shfl(m, 0);
        float ex = expf(e - m);
        float sum = ex;
        for (int off = 32; off; off >>= 1) sum += __shfl_down(sum, off);
        sum = __shfl(sum, 0);
        W_l[tid] = ex / sum;
    }
    __syncthreads();

    // main: thread = (pair pi, t-group); 16 t's each, partials to LDS
    {
        const int pi = tid & 255;
        const int tg = tid >> 8;           // 0..3
        const int p = ((blk & 3) << 8) + pi;
        const int t0 = tg << 4;
        const float2* a2 = (const float2*)amp;
        const float2* p2 = (const float2*)ph;
        float a0 = 0.f, a1 = 0.f, b0 = 0.f, b1 = 0.f;
#pragma unroll 4
        for (int t = t0; t < t0 + 16; ++t) {
            float2 av = a2[t * NP + p];
            float2 pv = p2[t * NP + p];
            float w = W_l[t], in = in_l[t];
            float ra0 = av.x * in * (__cosf(pv.x) + __sinf(pv.x));
            float ra1 = av.y * in * (__cosf(pv.y) + __sinf(pv.y));
            float wr0 = w * ra0, wr1 = w * ra1;
            a0 += wr0 * Gl[4 * t + 0];
            b0 += wr0 * Gl[4 * t + 2];
            a1 += wr1 * Gl[4 * t + 1];
            b1 += wr1 * Gl[4 * t + 3];
        }
        part4[tg][pi] = make_float4(a0, a1, b0, b1);
    }
    __syncthreads();

    if (tid < 256) {  // combine 4 partials (fixed order), write M0/M1/Qt4
        const int p = ((blk & 3) << 8) + tid;
        float4 s0 = part4[0][tid], s1 = part4[1][tid],
               s2 = part4[2][tid], s3 = part4[3][tid];
        float a0 = s0.x + s1.x + s2.x + s3.x;
        float a1 = s0.y + s1.y + s2.y + s3.y;
        float b0 = s0.z + s1.z + s2.z + s3.z;
        float b1 = s0.w + s1.w + s2.w + s3.w;
        ((float2*)(M0 + srow * ND))[p] = make_float2(a0, a1);
        ((float2*)(M1 + srow * ND))[p] = make_float2(b0, b1);
        ((float4*)Qt)[p * 64 + srow] =
            make_float4(a0 * a0 + a1 * a1, a0 * b0 + a1 * b1, b0 * b0 + b1 * b1, 0.f);
    }
}

// ---------------- K2: partial logits (8 rows x 1/4 p-range), R2 structure ----
// 256 blocks x 1024 threads: rg = blk>>2 (rows rg*8..+8), pc = blk&3
// (pairs pc*256..+256). Qt read = one aligned dwordx4/lane, 1 KB/wave.
// No fences/atomics — the kernel boundary is the global barrier.
__global__ void __launch_bounds__(1024)
k_logA(const float* __restrict__ x, const float* __restrict__ Qt,
       float* __restrict__ pglob) {
    __shared__ float4 xq[8][256];        // 32 KB: (x0^2, 2*x0*x1, x1^2, 0)
    __shared__ float part[16][8][64];    // 32 KB
    const int blk = blockIdx.x;
    const int tid = threadIdx.x;
    const int rg = blk >> 2, pc = blk & 3;
    const int r0 = rg * 8;

    {   // stage x chunk in quadratic form (coalesced float4)
        const int r = tid >> 7, i = tid & 127;
        float4 v = ((const float4*)(x + (r0 + r) * ND + pc * 512))[i];
        float4 q0, q1;
        q0.x = v.x * v.x; q0.y = 2.f * v.x * v.y; q0.z = v.y * v.y; q0.w = 0.f;
        q1.x = v.z * v.z; q1.y = 2.f * v.z * v.w; q1.z = v.w * v.w; q1.w = 0.f;
        xq[r][2 * i] = q0;
        xq[r][2 * i + 1] = q1;
    }
    __syncthreads();

    const int w = tid >> 6, s = tid & 63;
    {
        float acc[8] = {0.f, 0.f, 0.f, 0.f, 0.f, 0.f, 0.f, 0.f};
        const float4* qt4 = (const float4*)Qt + (pc * 256 + (w << 4)) * 64 + s;
#pragma unroll 4
        for (int j = 0; j < 16; ++j) {
            const int jj = (j + rg) & 15;           // skewed visit order
            const int pl = (w << 4) + jj;
            float4 q = qt4[jj * 64];                // aligned dwordx4, 1 KB/wave
#pragma unroll
            for (int r = 0; r < 8; ++r) {
                float4 xv = xq[r][pl];              // LDS broadcast
                acc[r] += xv.x * q.x + xv.y * q.y + xv.z * q.z;
            }
        }
#pragma unroll
        for (int r = 0; r < 8; ++r) part[w][r][s] = acc[r];
    }
    __syncthreads();

    if (tid < 512) {  // cross-wave reduce (fixed order), publish partial slot
        const int rr = tid >> 6;
        float l = 0.f;
#pragma unroll
        for (int k = 0; k < 16; ++k) l += part[k][rr][s];
        pglob[(pc * NB + r0 + rr) * NS + s] = l;
    }
}

// ---------------- K3: final logits + collapse + output; 2 rows/block ---------
// 256 blocks x 1024 threads (R2 verbatim). Fixed-order reduce of 4 slots,
// exact jax categorical, coalesced gather/write.
__global__ void __launch_bounds__(1024)
k_logB(const float* __restrict__ x, const float* __restrict__ pglob,
       const float* __restrict__ M0, const float* __restrict__ M1,
       float* __restrict__ out) {
    __shared__ float2 xs[2 * NP];      // 16 KB: two x rows, as pairs
    __shared__ int o_sh[2];
    const int blk = blockIdx.x;
    const int tid = threadIdx.x;
    const int r0 = 2 * blk;

    // stage 2 x rows (coalesced float4: 1024 of them)
    ((float4*)xs)[tid] = ((const float4*)(x + r0 * ND))[tid];

    if (tid < 128) {  // waves 0-1: row r0+w2; reduce slots + gumbel-max
        const int w2 = tid >> 6, s = tid & 63;
        const int row = r0 + w2;
        float l = 0.f;
#pragma unroll
        for (int c = 0; c < 4; ++c) l += pglob[(c * NB + row) * NS + s];
        unsigned n = (unsigned)(row * NS + s);
        unsigned t0u = 0u, t1u = n;
        threefry2x32(0u, 42u, t0u, t1u);
        unsigned bits = t0u ^ t1u;
        float u = (float)(bits >> 9) * (1.0f / 8388608.0f);
        u = fmaxf(u, 1.17549435e-38f);
        float g = -logf(-logf(u));
        float best = l + g;
        int bi = s;
        for (int off = 32; off; off >>= 1) {
            float ov = __shfl_down(best, off);
            int oi = __shfl_down(bi, off);
            if (ov > best || (ov == best && oi < bi)) { best = ov; bi = oi; }
        }
        if (s == 0) o_sh[w2] = bi;
    }
    __syncthreads();

#pragma unroll
    for (int r = 0; r < 2; ++r) {
        const int o = o_sh[r];
        const float2* m0p = (const float2*)(M0 + o * ND);
        const float2* m1p = (const float2*)(M1 + o * ND);
        const float2* xr = xs + r * NP;
        float2* op = (float2*)(out + (r0 + r) * ND);
        float2 xv = xr[tid], m0 = m0p[tid], m1 = m1p[tid];
        float2 rr;
        rr.x = xv.x * m0.x + xv.y * m1.x;
        rr.y = xv.x * m0.y + xv.y * m1.y;
        op[tid] = rr;
    }
}

extern "C" void kernel_launch(void* const* d_in, const int* in_sizes, int n_in,
                              void* d_out, int out_size, void* d_ws, size_t ws_size,
                              hipStream_t stream) {
    const float* x   = (const float*)d_in[0];  // [512,2048]
    const float* amp = (const float*)d_in[1];  // [64,2048]
    const float* ph  = (const float*)d_in[2];  // [64,2048]
    const float* G   = (const float*)d_in[3];  // [64,2,2]
    const float* E   = (const float*)d_in[4];  // [64,64]
    float* out = (float*)d_out;
    float* ws = (float*)d_ws;

    float* M0 = ws + OFF_M0;
    float* M1 = ws + OFF_M1;
    float* Qt = ws + OFF_QT;
    float* pp = ws + OFF_PART;

    k_MQ  <<<256, 1024, 0, stream>>>(amp, ph, G, E, M0, M1, Qt);
    k_logA<<<256, 1024, 0, stream>>>(x, Qt, pp);
    k_logB<<<256, 1024, 0, stream>>>(x, pp, M0, M1, out);
}

// Round 6
// 85.216 us; speedup vs baseline: 1.2494x; 1.0782x over previous
//
#include <hip/hip_runtime.h>
#include <math.h>

#define NB 512
#define NS 64
#define ND 2048
#define NP 1024   // ND/2

// ws layout (float offsets)
#define OFF_M0   0        // 131072 floats
#define OFF_M1   131072   // 131072 floats
#define OFF_R    262144   // 64*2048 = 131072 floats
#define OFF_W    393216   // 64*64   = 4096
#define OFF_QT   397312   // float4[1024][64] = 262144 floats (1 MB padded)
#define OFF_PART 659456   // [4][512][64] = 131072 floats

// ---------------- threefry2x32 (exact jax semantics, key=(0,42)) -------------
__device__ __forceinline__ unsigned rotl32(unsigned x, int d) {
    return (x << d) | (x >> (32 - d));
}

__device__ __forceinline__ void threefry2x32(unsigned k0, unsigned k1,
                                             unsigned& x0, unsigned& x1) {
    const unsigned ks0 = k0, ks1 = k1, ks2 = k0 ^ k1 ^ 0x1BD11BDAu;
    const int r0[4] = {13, 15, 26, 6};
    const int r1[4] = {17, 29, 16, 24};
    x0 += ks0; x1 += ks1;
#pragma unroll
    for (int i = 0; i < 4; ++i) { x0 += x1; x1 = rotl32(x1, r0[i]); x1 ^= x0; }
    x0 += ks1; x1 += ks2 + 1u;
#pragma unroll
    for (int i = 0; i < 4; ++i) { x0 += x1; x1 = rotl32(x1, r1[i]); x1 ^= x0; }
    x0 += ks2; x1 += ks0 + 2u;
#pragma unroll
    for (int i = 0; i < 4; ++i) { x0 += x1; x1 = rotl32(x1, r0[i]); x1 ^= x0; }
    x0 += ks0; x1 += ks1 + 3u;
#pragma unroll
    for (int i = 0; i < 4; ++i) { x0 += x1; x1 = rotl32(x1, r1[i]); x1 ^= x0; }
    x0 += ks1; x1 += ks2 + 4u;
#pragma unroll
    for (int i = 0; i < 4; ++i) { x0 += x1; x1 = rotl32(x1, r0[i]); x1 ^= x0; }
    x0 += ks2; x1 += ks0 + 5u;
}

// ---------------- K0: per-row norm + softmax(E row) + R = real_amp -----------
// (R2 verbatim) 64 blocks x 256 threads; block t handles amp row t + E row t.
__global__ void __launch_bounds__(256)
k_pre(const float* __restrict__ amp, const float* __restrict__ ph,
      const float* __restrict__ E, float* __restrict__ R,
      float* __restrict__ W) {
    __shared__ float in_sh;
    const int t = blockIdx.x;
    const int tid = threadIdx.x;

    if (tid < 16) {  // wave 0: norm of amp row t (exact original summation order)
        const float4* a4 = (const float4*)(amp + t * ND);
        float acc = 0.f;
#pragma unroll 8
        for (int i = 0; i < 32; ++i) {
            float4 v = a4[tid + 16 * i];
            acc += v.x * v.x + v.y * v.y + v.z * v.z + v.w * v.w;
        }
        acc += __shfl_down(acc, 8, 16);
        acc += __shfl_down(acc, 4, 16);
        acc += __shfl_down(acc, 2, 16);
        acc += __shfl_down(acc, 1, 16);
        if (tid == 0) in_sh = 1.0f / sqrtf(acc);
    }
    if (tid >= 64 && tid < 128) {  // wave 1: softmax of E row t (exact original)
        const int s = tid - 64;
        float e = E[t * NS + s];
        float m = e;
        for (int off = 32; off; off >>= 1) m = fmaxf(m, __shfl_down(m, off));
        m = __shfl(m, 0);
        float ex = expf(e - m);
        float sum = ex;
        for (int off = 32; off; off >>= 1) sum += __shfl_down(sum, off);
        sum = __shfl(sum, 0);
        W[t * NS + s] = ex / sum;
    }
    __syncthreads();

    const float in = in_sh;
    const float2* a2 = (const float2*)(amp + t * ND);
    const float2* p2 = (const float2*)(ph + t * ND);
    float2* r2 = (float2*)(R + t * ND);
#pragma unroll
    for (int k = 0; k < 4; ++k) {
        const int i = tid + 256 * k;
        float2 av = a2[i], pv = p2[i];
        float2 rv;
        rv.x = av.x * in * (__cosf(pv.x) + __sinf(pv.x));
        rv.y = av.y * in * (__cosf(pv.y) + __sinf(pv.y));
        r2[i] = rv;
    }
}

// ---------------- K1: M0/M1/Qt from precomputed R, W ------------------------
// (R2 verbatim except Qt write is one float4) 256 blocks x 1024 threads.
__global__ void __launch_bounds__(1024)
k_MQ(const float* __restrict__ R, const float* __restrict__ W,
     const float* __restrict__ G,
     float* __restrict__ M0, float* __restrict__ M1, float* __restrict__ Qt) {
    __shared__ float W_l[NS];
    __shared__ float Gl[NS * 4];
    __shared__ float4 part4[4][256];   // per-tgroup partial (a0,a1,b0,b1)
    const int blk = blockIdx.x;
    const int tid = threadIdx.x;
    const int srow = blk >> 2;

    if (tid < NS) W_l[tid] = W[srow * NS + tid];
    if (tid >= 256 && tid < 256 + NS * 4) Gl[tid - 256] = G[tid - 256];
    __syncthreads();

    {
        const int pi = tid & 255;
        const int tg = tid >> 8;           // 0..3
        const int p = ((blk & 3) << 8) + pi;
        const int t0 = tg << 4;
        const float2* r2 = (const float2*)R;
        float a0 = 0.f, a1 = 0.f, b0 = 0.f, b1 = 0.f;
#pragma unroll 4
        for (int j = 0; j < 16; ++j) {
            const int t = t0 + ((j + srow) & 15);   // skewed visit order
            float2 rv = r2[t * NP + p];
            float w = W_l[t];
            float wr0 = w * rv.x, wr1 = w * rv.y;
            a0 += wr0 * Gl[4 * t + 0];
            b0 += wr0 * Gl[4 * t + 2];
            a1 += wr1 * Gl[4 * t + 1];
            b1 += wr1 * Gl[4 * t + 3];
        }
        part4[tg][pi] = make_float4(a0, a1, b0, b1);
    }
    __syncthreads();

    if (tid < 256) {  // combine 4 partials (fixed order), write M0/M1/Qt4
        const int p = ((blk & 3) << 8) + tid;
        float4 s0 = part4[0][tid], s1 = part4[1][tid],
               s2 = part4[2][tid], s3 = part4[3][tid];
        float a0 = s0.x + s1.x + s2.x + s3.x;
        float a1 = s0.y + s1.y + s2.y + s3.y;
        float b0 = s0.z + s1.z + s2.z + s3.z;
        float b1 = s0.w + s1.w + s2.w + s3.w;
        float2 m0v = {a0, a1}, m1v = {b0, b1};
        ((float2*)(M0 + srow * ND))[p] = m0v;
        ((float2*)(M1 + srow * ND))[p] = m1v;
        ((float4*)Qt)[p * 64 + srow] =
            make_float4(a0 * a0 + a1 * a1, a0 * b0 + a1 * b1, b0 * b0 + b1 * b1, 0.f);
    }
}

// ---------------- K2a: partial logits (8 rows x 1/4 p-range) -----------------
// (R2 verbatim except Qt read is one aligned dwordx4, 1 KB/wave)
// 256 blocks x 1024 threads: rg = blk>>2 (rows rg*8..+8), pc = blk&3.
__global__ void __launch_bounds__(1024)
k_logA(const float* __restrict__ x, const float* __restrict__ Qt,
       float* __restrict__ pglob) {
    __shared__ float4 xq[8][256];        // 32 KB: (x0^2, 2*x0*x1, x1^2, 0)
    __shared__ float part[16][8][64];    // 32 KB
    const int blk = blockIdx.x;
    const int tid = threadIdx.x;
    const int rg = blk >> 2, pc = blk & 3;
    const int r0 = rg * 8;

    {   // stage x chunk in quadratic form (coalesced float4)
        const int r = tid >> 7, i = tid & 127;
        float4 v = ((const float4*)(x + (r0 + r) * ND + pc * 512))[i];
        float4 q0, q1;
        q0.x = v.x * v.x; q0.y = 2.f * v.x * v.y; q0.z = v.y * v.y; q0.w = 0.f;
        q1.x = v.z * v.z; q1.y = 2.f * v.z * v.w; q1.z = v.w * v.w; q1.w = 0.f;
        xq[r][2 * i] = q0;
        xq[r][2 * i + 1] = q1;
    }
    __syncthreads();

    const int w = tid >> 6, s = tid & 63;
    {
        float acc[8] = {0.f, 0.f, 0.f, 0.f, 0.f, 0.f, 0.f, 0.f};
        const float4* qt4 = (const float4*)Qt + (pc * 256 + (w << 4)) * 64 + s;
#pragma unroll 4
        for (int j = 0; j < 16; ++j) {
            const int jj = (j + rg) & 15;           // skewed visit order
            const int pl = (w << 4) + jj;
            float4 q = qt4[jj * 64];                // aligned dwordx4, 1 KB/wave
#pragma unroll
            for (int r = 0; r < 8; ++r) {
                float4 xv = xq[r][pl];              // LDS broadcast
                acc[r] += xv.x * q.x + xv.y * q.y + xv.z * q.z;
            }
        }
#pragma unroll
        for (int r = 0; r < 8; ++r) part[w][r][s] = acc[r];
    }
    __syncthreads();

    if (tid < 512) {  // cross-wave reduce (fixed order), publish partial slot
        const int rr = tid >> 6;
        float l = 0.f;
#pragma unroll
        for (int k = 0; k < 16; ++k) l += part[k][rr][s];
        pglob[(pc * NB + r0 + rr) * NS + s] = l;
    }
}

// ---------------- K2b: final logits + collapse + output; 2 rows/block --------
// (R2 verbatim) 256 blocks x 1024 threads.
__global__ void __launch_bounds__(1024)
k_logB(const float* __restrict__ x, const float* __restrict__ pglob,
       const float* __restrict__ M0, const float* __restrict__ M1,
       float* __restrict__ out) {
    __shared__ float2 xs[2 * NP];      // 16 KB: two x rows, as pairs
    __shared__ int o_sh[2];
    const int blk = blockIdx.x;
    const int tid = threadIdx.x;
    const int r0 = 2 * blk;

    // stage 2 x rows (coalesced float4: 1024 of them)
    ((float4*)xs)[tid] = ((const float4*)(x + r0 * ND))[tid];

    if (tid < 128) {  // waves 0-1: row r0+w2; reduce slots + gumbel-max
        const int w2 = tid >> 6, s = tid & 63;
        const int row = r0 + w2;
        float l = 0.f;
#pragma unroll
        for (int c = 0; c < 4; ++c) l += pglob[(c * NB + row) * NS + s];
        unsigned n = (unsigned)(row * NS + s);
        unsigned t0u = 0u, t1u = n;
        threefry2x32(0u, 42u, t0u, t1u);
        unsigned bits = t0u ^ t1u;
        float u = (float)(bits >> 9) * (1.0f / 8388608.0f);
        u = fmaxf(u, 1.17549435e-38f);
        float g = -logf(-logf(u));
        float best = l + g;
        int bi = s;
        for (int off = 32; off; off >>= 1) {
            float ov = __shfl_down(best, off);
            int oi = __shfl_down(bi, off);
            if (ov > best || (ov == best && oi < bi)) { best = ov; bi = oi; }
        }
        if (s == 0) o_sh[w2] = bi;
    }
    __syncthreads();

#pragma unroll
    for (int r = 0; r < 2; ++r) {
        const int o = o_sh[r];
        const float2* m0p = (const float2*)(M0 + o * ND);
        const float2* m1p = (const float2*)(M1 + o * ND);
        const float2* xr = xs + r * NP;
        float2* op = (float2*)(out + (r0 + r) * ND);
        float2 xv = xr[tid], m0 = m0p[tid], m1 = m1p[tid];
        float2 rr;
        rr.x = xv.x * m0.x + xv.y * m1.x;
        rr.y = xv.x * m0.y + xv.y * m1.y;
        op[tid] = rr;
    }
}

extern "C" void kernel_launch(void* const* d_in, const int* in_sizes, int n_in,
                              void* d_out, int out_size, void* d_ws, size_t ws_size,
                              hipStream_t stream) {
    const float* x   = (const float*)d_in[0];  // [512,2048]
    const float* amp = (const float*)d_in[1];  // [64,2048]
    const float* ph  = (const float*)d_in[2];  // [64,2048]
    const float* G   = (const float*)d_in[3];  // [64,2,2]
    const float* E   = (const float*)d_in[4];  // [64,64]
    float* out = (float*)d_out;
    float* ws = (float*)d_ws;

    float* M0 = ws + OFF_M0;
    float* M1 = ws + OFF_M1;
    float* R  = ws + OFF_R;
    float* W  = ws + OFF_W;
    float* Qt = ws + OFF_QT;
    float* pp = ws + OFF_PART;

    k_pre <<<64, 256, 0, stream>>>(amp, ph, E, R, W);
    k_MQ  <<<256, 1024, 0, stream>>>(R, W, G, M0, M1, Qt);
    k_logA<<<256, 1024, 0, stream>>>(x, Qt, pp);
    k_logB<<<256, 1024, 0, stream>>>(x, pp, M0, M1, out);
}